// Round 14
// baseline (228.654 us; speedup 1.0000x reference)
//
#include <hip/hip_runtime.h>
#include <math.h>

namespace {
constexpr int B = 8, C = 128, N = 2048, M = 512;
constexpr int NSPLIT = 8;       // part (NSPLIT*B*C*M fp32 = 16.8MB) must fit split region (25.2MB)
constexpr int MBLK = 16;        // energy m-tiles -> rowpart slots
constexpr float INV_SQRT_C = 0.08838834764831845f;  // 1/sqrt(128)
}

typedef __attribute__((ext_vector_type(8))) short short8;
typedef __attribute__((ext_vector_type(16))) float f32x16;
typedef unsigned short ushort_t;
typedef unsigned int u32;

__device__ inline ushort_t f2bf(float f) {   // round-to-nearest-even bf16
  union { float f; u32 u; } a; a.f = f;
  u32 r = a.u + 0x7fffu + ((a.u >> 16) & 1u);
  return (ushort_t)(r >> 16);
}
__device__ inline float bf2f(ushort_t h) {
  union { u32 u; float f; } a; a.u = ((u32)h) << 16; return a.f;
}

// async 16B global -> LDS (wave-uniform base + lane*16 dest; mapping linear in t)
__device__ __forceinline__ void gl_lds16(const ushort_t* g, ushort_t* l) {
  __builtin_amdgcn_global_load_lds(
      (const __attribute__((address_space(1))) unsigned int*)g,
      (__attribute__((address_space(3))) unsigned int*)l, 16, 0, 0);
}

// -- q,k: 3-term bf16 split, k-chunk-major [term][b][kc][n][8]; v: bf16 [b][c][n] --
__global__ __launch_bounds__(256) void qkv_kernel(
    const float* __restrict__ x, const float* __restrict__ Wq,
    const float* __restrict__ Wk, const float* __restrict__ Wv,
    ushort_t* __restrict__ split, ushort_t* __restrict__ vbf) {
  const size_t TERM = (size_t)B * N * C;
  int kc = blockIdx.x;             // output-channel chunk (8 channels)
  int o0 = kc * 8;
  int n = blockIdx.y * 256 + threadIdx.x;
  int b = blockIdx.z;
  const float* xb = x + (size_t)b * C * N + n;
  float aq[8] = {}, ak[8] = {}, av[8] = {};
  #pragma unroll 4
  for (int c = 0; c < C; ++c) {
    float xv = xb[(size_t)c * N];
    #pragma unroll
    for (int j = 0; j < 8; ++j) {   // W loads wave-uniform -> s_loads
      aq[j] = fmaf(Wq[(o0 + j) * C + c], xv, aq[j]);
      ak[j] = fmaf(Wk[(o0 + j) * C + c], xv, ak[j]);
      av[j] = fmaf(Wv[(o0 + j) * C + c], xv, av[j]);
    }
  }
  #pragma unroll
  for (int j = 0; j < 8; ++j)
    vbf[((size_t)b * C + o0 + j) * N + n] = f2bf(av[j]);
  size_t rowoff = ((size_t)b * 16 + kc) * (size_t)N * 8 + (size_t)n * 8;
  #pragma unroll
  for (int tt = 0; tt < 3; ++tt) {
    short8 qv, kv;
    #pragma unroll
    for (int j = 0; j < 8; ++j) {
      ushort_t h = f2bf(aq[j]); qv[j] = (short)h; aq[j] -= bf2f(h);
      h = f2bf(ak[j]);          kv[j] = (short)h; ak[j] -= bf2f(h);
    }
    *(short8*)&split[tt * TERM + rowoff]       = qv;
    *(short8*)&split[(3 + tt) * TERM + rowoff] = kv;
  }
}

// ---- Ae[b,n,m] = exp(q.k/sqrt(C)) via 6-product 3-term-split MFMA ------
// FROZEN arithmetic: MFMA order per accumulator, exp, LDS reduce verbatim.
// TERMINAL r6 configuration (best measured: 227.1us total, reproduced).
// Counted-vmcnt LDS staging (T4): raw s_barrier + s_waitcnt vmcnt(6) keeps
// the next step's 6 loads in flight across the barrier. -17us vs direct
// global->reg (r0); the one structural win of the session.
// Ledger of refuted variants: vmcnt(0)-drain staging (r1, -8%); register
// double-buffer (r2, -20%); wider 256m tile (r7, -12%); setprio around
// MFMA (r8, -22%); Ae-recompute in consumers (r5, -22% total); staged
// colsum / T14-out / nt-loads (r8/r10/r12: within noise on total).
__global__ __launch_bounds__(256) void energy_kernel(
    const ushort_t* __restrict__ split,
    float* __restrict__ Ae, float* __restrict__ rowpart) {
  // staging: 2 bufs x 24KB (A: 3 terms x [kc-half][128 rows][8ch] bf16 = 12KB, B same)
  // red reduction only live after the loop's final barrier -> union is safe
  __shared__ __align__(16) union {
    ushort_t stg[2][12288];                                // 2 x 24KB
    struct { float red[128][64]; float red2[128][2]; } r;  // 33KB
  } sm;
  const size_t TERM = (size_t)B * N * C;
  const size_t ROW8 = (size_t)N * 8;       // elements per kc-row
  int t = threadIdx.x;
  int lane = t & 63, w = t >> 6;
  int wn = w & 1, wm = w >> 1;             // wave quadrant
  // XCD-aware 4x4 supertile assignment (r3, neutral/harmless, kept)
  int lin = blockIdx.y * 16 + blockIdx.x;
  int xcd = lin & 7, slot = lin >> 3;
  int st = xcd * 2 + (slot >> 4);
  int wi = slot & 15;
  int mb = (st & 3) * 4 + (wi & 3);
  int nb = (st >> 2) * 4 + (wi >> 2);
  int m0 = mb * 128, n0 = nb * 128, b = blockIdx.z;
  int lr = lane & 31, lq = lane >> 5;

  // staging source: thread t stages row (t&127) of kc-half (t>>7), one 16B
  // short8 per term per side. LDS slab: [side-term(6)][kc-half][row][8ch].
  const ushort_t* gA = split + (size_t)b * 16 * ROW8
                     + (size_t)(t >> 7) * ROW8 + ((size_t)n0 + (t & 127)) * 8;
  const ushort_t* gB = split + 3 * TERM + (size_t)b * 16 * ROW8
                     + (size_t)(t >> 7) * ROW8 + ((size_t)m0 + (t & 127)) * 8;
  const int aoff = (lq * 128 + wn * 64 + lr) * 8;   // ushort idx in a term slab
  const int boff = (lq * 128 + wm * 64 + lr) * 8;

#define STAGE_STEP(buf_, s_) do {                                            \
    size_t so_ = (size_t)(2 * (s_)) * ROW8;                                  \
    _Pragma("unroll")                                                        \
    for (int tt = 0; tt < 3; ++tt) {                                         \
      gl_lds16(gA + (size_t)tt * TERM + so_, &sm.stg[buf_][tt * 2048 + t * 8]); \
      gl_lds16(gB + (size_t)tt * TERM + so_, &sm.stg[buf_][(3 + tt) * 2048 + t * 8]); \
    }                                                                        \
  } while (0)

  f32x16 acc[2][2] = {};
  STAGE_STEP(0, 0);                        // prologue: 2-deep prefetch
  STAGE_STEP(1, 1);                        // (12 loads in flight)
  #pragma unroll
  for (int s = 0; s < 8; ++s) {            // K = 8 steps x 16 channels
    const int cur = s & 1;
    if (s < 7) asm volatile("s_waitcnt vmcnt(6)" ::: "memory");  // step s done,
    else       asm volatile("s_waitcnt vmcnt(0)" ::: "memory");  // s+1 in flight
    __builtin_amdgcn_sched_barrier(0);
    __builtin_amdgcn_s_barrier();          // all waves: buf[cur] ready
    short8 aT[3][2], bT[3][2];
    #pragma unroll
    for (int tt = 0; tt < 3; ++tt)
      #pragma unroll
      for (int i = 0; i < 2; ++i) {        // i = 32-point sub-tile
        aT[tt][i] = *(const short8*)&sm.stg[cur][tt * 2048 + aoff + i * 256];
        bT[tt][i] = *(const short8*)&sm.stg[cur][(3 + tt) * 2048 + boff + i * 256];
      }
    #pragma unroll
    for (int mt = 0; mt < 2; ++mt)
      #pragma unroll
      for (int nt = 0; nt < 2; ++nt) {
        acc[mt][nt] = __builtin_amdgcn_mfma_f32_32x32x16_bf16(aT[0][mt], bT[0][nt], acc[mt][nt], 0, 0, 0);
        acc[mt][nt] = __builtin_amdgcn_mfma_f32_32x32x16_bf16(aT[1][mt], bT[0][nt], acc[mt][nt], 0, 0, 0);
        acc[mt][nt] = __builtin_amdgcn_mfma_f32_32x32x16_bf16(aT[0][mt], bT[1][nt], acc[mt][nt], 0, 0, 0);
        acc[mt][nt] = __builtin_amdgcn_mfma_f32_32x32x16_bf16(aT[2][mt], bT[0][nt], acc[mt][nt], 0, 0, 0);
        acc[mt][nt] = __builtin_amdgcn_mfma_f32_32x32x16_bf16(aT[1][mt], bT[1][nt], acc[mt][nt], 0, 0, 0);
        acc[mt][nt] = __builtin_amdgcn_mfma_f32_32x32x16_bf16(aT[0][mt], bT[2][nt], acc[mt][nt], 0, 0, 0);
      }
    __builtin_amdgcn_sched_barrier(0);     // keep reads/MFMA above the barrier
    __builtin_amdgcn_s_barrier();          // all waves done reading buf[cur]
    if (s < 6) STAGE_STEP(cur, s + 2);     // overwrite freed buffer
  }
#undef STAGE_STEP
  // epilogue (FROZEN modulo sm.r.* names); final loop barrier guarantees all
  // LDS reads drained before the union is reused for red
  int lc = lr;
  #pragma unroll
  for (int mt = 0; mt < 2; ++mt) {
    #pragma unroll
    for (int reg = 0; reg < 16; ++reg) {
      int row = (reg & 3) + 8 * (reg >> 2) + 4 * lq;   // C/D layout (m74/m101)
      int rloc = wn * 64 + mt * 32 + row;
      float e0 = expf(acc[mt][0][reg] * INV_SQRT_C);
      float e1 = expf(acc[mt][1][reg] * INV_SQRT_C);
      float* pA = Ae + ((size_t)b * N + n0 + rloc) * N + m0 + wm * 64 + lc;
      __builtin_nontemporal_store(e0, pA);        // r4: neutral, kept
      __builtin_nontemporal_store(e1, pA + 32);
      sm.r.red[rloc][wm * 32 + lc] = e0 + e1;     // disjoint slots, no race
    }
  }
  __syncthreads();
  {
    int row = t >> 1, h = t & 1;
    float ssum = 0.f;
    #pragma unroll
    for (int j0 = 0; j0 < 32; ++j0) {
      int j = (j0 + (t & 31)) & 31;        // bank rotation: 2-way max (free)
      ssum += sm.r.red[row][h * 32 + j];
    }
    sm.r.red2[row][h] = ssum;
  }
  __syncthreads();
  if (t < 128)
    rowpart[(size_t)mb * (B * N) + b * N + n0 + t] = sm.r.red2[t][0] + sm.r.red2[t][1];
}

// --- selpart[nch][b*N+m] = sum_{n in chunk} Ae[b,n,m] * invr[b,n] ------
// FROZEN arithmetic. invr computed inline with the exact rowred bits
// (ascending 16-slot fp32 sum, then 1/s). r14: each thread owns FOUR
// adjacent columns via float4 loads (1KB/wave/row vs 256B) — barrier-free
// (r12's staged variant serialized a pure stream; this only widens it).
// Per-column chain is the same serial ascending-n fmaf sequence with the
// same sinv bits -> selpart bit-identical. Grid x: N/256 -> N/1024.
__global__ __launch_bounds__(256) void colsum_kernel(
    const float* __restrict__ Ae, const float* __restrict__ rowpart,
    float* __restrict__ selpart) {
  __shared__ float sinv[256];
  int t = threadIdx.x;
  int m = blockIdx.x * 1024 + t * 4;
  int nch = blockIdx.y, b = blockIdx.z;
  int n0 = nch * (N / 8);
  {
    int n = n0 + t;                  // 256 threads <-> 256 chunk rows
    float s = 0.f;
    #pragma unroll
    for (int sl = 0; sl < MBLK; ++sl)
      s += rowpart[(size_t)sl * (B * N) + b * N + n];
    sinv[t] = 1.0f / s;
  }
  __syncthreads();
  const float* Ab = Ae + (size_t)b * N * N;
  float4 acc = make_float4(0.f, 0.f, 0.f, 0.f);
  #pragma unroll 8
  for (int n = n0; n < n0 + N / 8; ++n) {
    float4 v = *(const float4*)&Ab[(size_t)n * N + m];
    float s = sinv[n - n0];          // broadcast (no bank conflict)
    acc.x = fmaf(v.x, s, acc.x);     // each column: same fmaf chain as r13
    acc.y = fmaf(v.y, s, acc.y);
    acc.z = fmaf(v.z, s, acc.z);
    acc.w = fmaf(v.w, s, acc.w);
  }
  *(float4*)&selpart[(size_t)nch * (B * N) + b * N + m] = acc;
}

// -- exact stable-descending top-k; selred fused with the SAME ascending
// 8-chunk sum order as r5's selred (bit-identical sel) -------------------
__global__ __launch_bounds__(256) void topk_kernel(
    const float* __restrict__ selpart, int* __restrict__ idx) {
  __shared__ float s[N];
  __shared__ int rsum[64][4];
  int b = blockIdx.y;
  int t = threadIdx.x;
  for (int i = t; i < N; i += 256) {
    float v_ = 0.f;
    #pragma unroll
    for (int nch = 0; nch < 8; ++nch)
      v_ += selpart[(size_t)nch * (B * N) + b * N + i];
    s[i] = v_;
  }
  __syncthreads();
  int i = blockIdx.x * 64 + (t & 63);
  int jc = t >> 6;
  float val = s[i];
  int r = 0;
  for (int j = jc * 512; j < jc * 512 + 512; ++j) {
    float sj = s[j];
    r += (sj > val || (sj == val && j < i)) ? 1 : 0;
  }
  rsum[t & 63][jc] = r;
  __syncthreads();
  if (t < 64) {
    int rank = rsum[t][0] + rsum[t][1] + rsum[t][2] + rsum[t][3];
    if (rank < M) idx[b * M + rank] = blockIdx.x * 64 + t;
  }
}

// ---- out partials via bf16 MFMA: m-tile 64 -> 512 blocks, 2/CU --------
// rinv computed inline with the exact rowred bits (same sum order + 1/s).
__global__ __launch_bounds__(256) void out_kernel(
    const float* __restrict__ Ae, const float* __restrict__ rowpart,
    const ushort_t* __restrict__ vbf, const int* __restrict__ idx,
    float* __restrict__ part) {
  __shared__ ushort_t sc[64][72];    // scores bf16, stride 144B (16B-aligned)
  __shared__ ushort_t vt[128][72];   // v bf16
  __shared__ int ridx[64];
  __shared__ float rinv[64];
  int t = threadIdx.x;
  int m0 = blockIdx.x * 64;
  int ns = blockIdx.y;
  int b = blockIdx.z;
  if (t < 64) {
    int r = idx[b * M + m0 + t];
    ridx[t] = r;
    float s = 0.f;
    #pragma unroll
    for (int sl = 0; sl < MBLK; ++sl)
      s += rowpart[(size_t)sl * (B * N) + b * N + r];
    rinv[t] = 1.0f / s;
  }
  __syncthreads();
  int lane = t & 63, w = t >> 6;
  int wc = w & 1, wm = w >> 1;       // c-half (64ch), m-half (32)
  int lr = lane & 31, lq = lane >> 5;
  f32x16 acc[2] = {};                // ct over two 32-ch subtiles
  int nbeg = ns * (N / NSPLIT);      // 256-wide K range
  for (int kb = 0; kb < N / NSPLIT; kb += 64) {
    __syncthreads();
    #pragma unroll
    for (int it = 0; it < 16; ++it) {   // scores: 64 rows x 64 cols
      int ii = it * 256 + t;            // 0..4095
      int r = ii >> 6, cn = ii & 63;
      float sv = Ae[((size_t)b * N + ridx[r]) * N + nbeg + kb + cn] * rinv[r];
      sc[r][cn] = f2bf(sv);
    }
    #pragma unroll
    for (int it = 0; it < 4; ++it) {    // v: 128 rows x 64 cols, short8 copies
      int u = it * 256 + t;             // 0..1023 vec-units
      int r = u >> 3, seg = u & 7;
      *(short8*)&vt[r][seg * 8] =
          *(const short8*)&vbf[((size_t)b * C + r) * N + nbeg + kb + seg * 8];
    }
    __syncthreads();
    #pragma unroll
    for (int ks = 0; ks < 4; ++ks) {
      short8 bf_ = *(const short8*)&sc[wm * 32 + lr][ks * 16 + lq * 8];
      #pragma unroll
      for (int ct = 0; ct < 2; ++ct) {
        short8 af = *(const short8*)&vt[wc * 64 + ct * 32 + lr][ks * 16 + lq * 8];
        acc[ct] = __builtin_amdgcn_mfma_f32_32x32x16_bf16(af, bf_, acc[ct], 0, 0, 0);
      }
    }
  }
  float* pb = part + ((size_t)ns * B + b) * C * M;
  #pragma unroll
  for (int ct = 0; ct < 2; ++ct) {
    #pragma unroll
    for (int reg = 0; reg < 16; ++reg) {
      int crow = wc * 64 + ct * 32 + (reg & 3) + 8 * (reg >> 2) + 4 * lq;
      pb[(size_t)crow * M + m0 + wm * 32 + lr] = acc[ct][reg];
    }
  }
}

// ---- deterministic reduce of the n-splits (float4, same per-elem order) --
__global__ __launch_bounds__(256) void reduce_kernel(
    const float* __restrict__ part, float* __restrict__ out) {
  int i = (blockIdx.x * 256 + threadIdx.x) * 4;
  float4 a = make_float4(0.f, 0.f, 0.f, 0.f);
  #pragma unroll
  for (int ns = 0; ns < NSPLIT; ++ns) {
    float4 p = *(const float4*)&part[(size_t)ns * (B * C * M) + i];
    a.x += p.x; a.y += p.y; a.z += p.z; a.w += p.w;
  }
  *(float4*)&out[i] = a;
}

extern "C" void kernel_launch(void* const* d_in, const int* in_sizes, int n_in,
                              void* d_out, int out_size, void* d_ws, size_t ws_size,
                              hipStream_t stream) {
  const float* x  = (const float*)d_in[0];
  const float* Wq = (const float*)d_in[1];
  const float* Wk = (const float*)d_in[2];
  const float* Wv = (const float*)d_in[3];
  float* out = (float*)d_out;

  const size_t TSZ = (size_t)B * N * C;
  ushort_t* split = (ushort_t*)d_ws;                 // 6 * TSZ bf16 = 25.2 MB
  ushort_t* vbf   = split + 6 * TSZ;                 // TSZ bf16 = 4.2 MB
  float* Ae       = (float*)(vbf + TSZ);             // 134.2 MB
  float* rowpart  = Ae + (size_t)B * N * N;          // 16 * B*N
  float* selpart  = rowpart + (size_t)MBLK * B * N;  // 8 * B*N
  int*   idx      = (int*)(selpart + (size_t)8 * B * N);  // B*M
  // part overlays split only (dead after energy); vbf stays live for out_kernel
  float* part     = (float*)split;

  qkv_kernel<<<dim3(16, N / 256, B), 256, 0, stream>>>(x, Wq, Wk, Wv, split, vbf);
  energy_kernel<<<dim3(N / 128, N / 128, B), 256, 0, stream>>>(split, Ae, rowpart);
  colsum_kernel<<<dim3(N / 1024, 8, B), 256, 0, stream>>>(Ae, rowpart, selpart);
  topk_kernel<<<dim3(N / 64, B), 256, 0, stream>>>(selpart, idx);
  out_kernel<<<dim3(M / 64, NSPLIT, B), 256, 0, stream>>>(Ae, rowpart, vbf, idx, part);
  reduce_kernel<<<dim3(B * C * M / 1024), 256, 0, stream>>>(part, out);
}

// Round 15
// 225.453 us; speedup vs baseline: 1.0142x; 1.0142x over previous
//
#include <hip/hip_runtime.h>
#include <math.h>

namespace {
constexpr int B = 8, C = 128, N = 2048, M = 512;
constexpr int NSPLIT = 8;       // part (NSPLIT*B*C*M fp32 = 16.8MB) must fit split region (25.2MB)
constexpr int MBLK = 16;        // energy m-tiles -> rowpart slots
constexpr float INV_SQRT_C = 0.08838834764831845f;  // 1/sqrt(128)
}

typedef __attribute__((ext_vector_type(8))) short short8;
typedef __attribute__((ext_vector_type(16))) float f32x16;
typedef unsigned short ushort_t;
typedef unsigned int u32;

__device__ inline ushort_t f2bf(float f) {   // round-to-nearest-even bf16
  union { float f; u32 u; } a; a.f = f;
  u32 r = a.u + 0x7fffu + ((a.u >> 16) & 1u);
  return (ushort_t)(r >> 16);
}
__device__ inline float bf2f(ushort_t h) {
  union { u32 u; float f; } a; a.u = ((u32)h) << 16; return a.f;
}

// async 16B global -> LDS (wave-uniform base + lane*16 dest; mapping linear in t)
__device__ __forceinline__ void gl_lds16(const ushort_t* g, ushort_t* l) {
  __builtin_amdgcn_global_load_lds(
      (const __attribute__((address_space(1))) unsigned int*)g,
      (__attribute__((address_space(3))) unsigned int*)l, 16, 0, 0);
}

// -- q,k: 3-term bf16 split, k-chunk-major [term][b][kc][n][8]; v: bf16 [b][c][n] --
__global__ __launch_bounds__(256) void qkv_kernel(
    const float* __restrict__ x, const float* __restrict__ Wq,
    const float* __restrict__ Wk, const float* __restrict__ Wv,
    ushort_t* __restrict__ split, ushort_t* __restrict__ vbf) {
  const size_t TERM = (size_t)B * N * C;
  int kc = blockIdx.x;             // output-channel chunk (8 channels)
  int o0 = kc * 8;
  int n = blockIdx.y * 256 + threadIdx.x;
  int b = blockIdx.z;
  const float* xb = x + (size_t)b * C * N + n;
  float aq[8] = {}, ak[8] = {}, av[8] = {};
  #pragma unroll 4
  for (int c = 0; c < C; ++c) {
    float xv = xb[(size_t)c * N];
    #pragma unroll
    for (int j = 0; j < 8; ++j) {   // W loads wave-uniform -> s_loads
      aq[j] = fmaf(Wq[(o0 + j) * C + c], xv, aq[j]);
      ak[j] = fmaf(Wk[(o0 + j) * C + c], xv, ak[j]);
      av[j] = fmaf(Wv[(o0 + j) * C + c], xv, av[j]);
    }
  }
  #pragma unroll
  for (int j = 0; j < 8; ++j)
    vbf[((size_t)b * C + o0 + j) * N + n] = f2bf(av[j]);
  size_t rowoff = ((size_t)b * 16 + kc) * (size_t)N * 8 + (size_t)n * 8;
  #pragma unroll
  for (int tt = 0; tt < 3; ++tt) {
    short8 qv, kv;
    #pragma unroll
    for (int j = 0; j < 8; ++j) {
      ushort_t h = f2bf(aq[j]); qv[j] = (short)h; aq[j] -= bf2f(h);
      h = f2bf(ak[j]);          kv[j] = (short)h; ak[j] -= bf2f(h);
    }
    *(short8*)&split[tt * TERM + rowoff]       = qv;
    *(short8*)&split[(3 + tt) * TERM + rowoff] = kv;
  }
}

// ---- Ae[b,n,m] = exp(q.k/sqrt(C)) via 6-product 3-term-split MFMA ------
// FROZEN arithmetic: MFMA order per accumulator, exp, LDS reduce verbatim.
// TERMINAL r6/r13 configuration (best measured: 227.14us total).
// Counted-vmcnt LDS staging (T4): raw s_barrier + s_waitcnt vmcnt(6) keeps
// the next step's 6 loads in flight across the barrier. -17us vs direct
// global->reg (r0); the one structural win of the session.
// Ledger of refuted variants: vmcnt(0)-drain staging (r1, -8%); register
// double-buffer (r2, -20%); wider 256m tile (r7, -12%); setprio around
// MFMA (r8, -22%); Ae-recompute in consumers (r5, -22% total); staged
// colsum (r12), float4 colsum (r14), T14-out / nt-loads (r8/r10): all
// within noise on total.
__global__ __launch_bounds__(256) void energy_kernel(
    const ushort_t* __restrict__ split,
    float* __restrict__ Ae, float* __restrict__ rowpart) {
  // staging: 2 bufs x 24KB (A: 3 terms x [kc-half][128 rows][8ch] bf16 = 12KB, B same)
  // red reduction only live after the loop's final barrier -> union is safe
  __shared__ __align__(16) union {
    ushort_t stg[2][12288];                                // 2 x 24KB
    struct { float red[128][64]; float red2[128][2]; } r;  // 33KB
  } sm;
  const size_t TERM = (size_t)B * N * C;
  const size_t ROW8 = (size_t)N * 8;       // elements per kc-row
  int t = threadIdx.x;
  int lane = t & 63, w = t >> 6;
  int wn = w & 1, wm = w >> 1;             // wave quadrant
  // XCD-aware 4x4 supertile assignment (r3, neutral/harmless, kept)
  int lin = blockIdx.y * 16 + blockIdx.x;
  int xcd = lin & 7, slot = lin >> 3;
  int st = xcd * 2 + (slot >> 4);
  int wi = slot & 15;
  int mb = (st & 3) * 4 + (wi & 3);
  int nb = (st >> 2) * 4 + (wi >> 2);
  int m0 = mb * 128, n0 = nb * 128, b = blockIdx.z;
  int lr = lane & 31, lq = lane >> 5;

  // staging source: thread t stages row (t&127) of kc-half (t>>7), one 16B
  // short8 per term per side. LDS slab: [side-term(6)][kc-half][row][8ch].
  const ushort_t* gA = split + (size_t)b * 16 * ROW8
                     + (size_t)(t >> 7) * ROW8 + ((size_t)n0 + (t & 127)) * 8;
  const ushort_t* gB = split + 3 * TERM + (size_t)b * 16 * ROW8
                     + (size_t)(t >> 7) * ROW8 + ((size_t)m0 + (t & 127)) * 8;
  const int aoff = (lq * 128 + wn * 64 + lr) * 8;   // ushort idx in a term slab
  const int boff = (lq * 128 + wm * 64 + lr) * 8;

#define STAGE_STEP(buf_, s_) do {                                            \
    size_t so_ = (size_t)(2 * (s_)) * ROW8;                                  \
    _Pragma("unroll")                                                        \
    for (int tt = 0; tt < 3; ++tt) {                                         \
      gl_lds16(gA + (size_t)tt * TERM + so_, &sm.stg[buf_][tt * 2048 + t * 8]); \
      gl_lds16(gB + (size_t)tt * TERM + so_, &sm.stg[buf_][(3 + tt) * 2048 + t * 8]); \
    }                                                                        \
  } while (0)

  f32x16 acc[2][2] = {};
  STAGE_STEP(0, 0);                        // prologue: 2-deep prefetch
  STAGE_STEP(1, 1);                        // (12 loads in flight)
  #pragma unroll
  for (int s = 0; s < 8; ++s) {            // K = 8 steps x 16 channels
    const int cur = s & 1;
    if (s < 7) asm volatile("s_waitcnt vmcnt(6)" ::: "memory");  // step s done,
    else       asm volatile("s_waitcnt vmcnt(0)" ::: "memory");  // s+1 in flight
    __builtin_amdgcn_sched_barrier(0);
    __builtin_amdgcn_s_barrier();          // all waves: buf[cur] ready
    short8 aT[3][2], bT[3][2];
    #pragma unroll
    for (int tt = 0; tt < 3; ++tt)
      #pragma unroll
      for (int i = 0; i < 2; ++i) {        // i = 32-point sub-tile
        aT[tt][i] = *(const short8*)&sm.stg[cur][tt * 2048 + aoff + i * 256];
        bT[tt][i] = *(const short8*)&sm.stg[cur][(3 + tt) * 2048 + boff + i * 256];
      }
    #pragma unroll
    for (int mt = 0; mt < 2; ++mt)
      #pragma unroll
      for (int nt = 0; nt < 2; ++nt) {
        acc[mt][nt] = __builtin_amdgcn_mfma_f32_32x32x16_bf16(aT[0][mt], bT[0][nt], acc[mt][nt], 0, 0, 0);
        acc[mt][nt] = __builtin_amdgcn_mfma_f32_32x32x16_bf16(aT[1][mt], bT[0][nt], acc[mt][nt], 0, 0, 0);
        acc[mt][nt] = __builtin_amdgcn_mfma_f32_32x32x16_bf16(aT[0][mt], bT[1][nt], acc[mt][nt], 0, 0, 0);
        acc[mt][nt] = __builtin_amdgcn_mfma_f32_32x32x16_bf16(aT[2][mt], bT[0][nt], acc[mt][nt], 0, 0, 0);
        acc[mt][nt] = __builtin_amdgcn_mfma_f32_32x32x16_bf16(aT[1][mt], bT[1][nt], acc[mt][nt], 0, 0, 0);
        acc[mt][nt] = __builtin_amdgcn_mfma_f32_32x32x16_bf16(aT[0][mt], bT[2][nt], acc[mt][nt], 0, 0, 0);
      }
    __builtin_amdgcn_sched_barrier(0);     // keep reads/MFMA above the barrier
    __builtin_amdgcn_s_barrier();          // all waves done reading buf[cur]
    if (s < 6) STAGE_STEP(cur, s + 2);     // overwrite freed buffer
  }
#undef STAGE_STEP
  // epilogue (FROZEN modulo sm.r.* names); final loop barrier guarantees all
  // LDS reads drained before the union is reused for red
  int lc = lr;
  #pragma unroll
  for (int mt = 0; mt < 2; ++mt) {
    #pragma unroll
    for (int reg = 0; reg < 16; ++reg) {
      int row = (reg & 3) + 8 * (reg >> 2) + 4 * lq;   // C/D layout (m74/m101)
      int rloc = wn * 64 + mt * 32 + row;
      float e0 = expf(acc[mt][0][reg] * INV_SQRT_C);
      float e1 = expf(acc[mt][1][reg] * INV_SQRT_C);
      float* pA = Ae + ((size_t)b * N + n0 + rloc) * N + m0 + wm * 64 + lc;
      __builtin_nontemporal_store(e0, pA);        // r4: neutral, kept
      __builtin_nontemporal_store(e1, pA + 32);
      sm.r.red[rloc][wm * 32 + lc] = e0 + e1;     // disjoint slots, no race
    }
  }
  __syncthreads();
  {
    int row = t >> 1, h = t & 1;
    float ssum = 0.f;
    #pragma unroll
    for (int j0 = 0; j0 < 32; ++j0) {
      int j = (j0 + (t & 31)) & 31;        // bank rotation: 2-way max (free)
      ssum += sm.r.red[row][h * 32 + j];
    }
    sm.r.red2[row][h] = ssum;
  }
  __syncthreads();
  if (t < 128)
    rowpart[(size_t)mb * (B * N) + b * N + n0 + t] = sm.r.red2[t][0] + sm.r.red2[t][1];
}

// --- selpart[nch][b*N+m] = sum_{n in chunk} Ae[b,n,m] * invr[b,n] ------
// FROZEN arithmetic. invr computed inline with the exact rowred bits
// (ascending 16-slot fp32 sum, then 1/s); fmaf chain order unchanged.
__global__ __launch_bounds__(256) void colsum_kernel(
    const float* __restrict__ Ae, const float* __restrict__ rowpart,
    float* __restrict__ selpart) {
  __shared__ float sinv[256];
  int t = threadIdx.x;
  int m = blockIdx.x * 256 + t;
  int nch = blockIdx.y, b = blockIdx.z;
  int n0 = nch * (N / 8);
  {
    int n = n0 + t;                  // 256 threads <-> 256 chunk rows
    float s = 0.f;
    #pragma unroll
    for (int sl = 0; sl < MBLK; ++sl)
      s += rowpart[(size_t)sl * (B * N) + b * N + n];
    sinv[t] = 1.0f / s;
  }
  __syncthreads();
  const float* Ab = Ae + (size_t)b * N * N;
  float acc = 0.f;
  #pragma unroll 8
  for (int n = n0; n < n0 + N / 8; ++n)
    acc = fmaf(Ab[(size_t)n * N + m], sinv[n - n0], acc);
  selpart[(size_t)nch * (B * N) + b * N + m] = acc;
}

// -- exact stable-descending top-k; selred fused with the SAME ascending
// 8-chunk sum order as r5's selred (bit-identical sel) -------------------
__global__ __launch_bounds__(256) void topk_kernel(
    const float* __restrict__ selpart, int* __restrict__ idx) {
  __shared__ float s[N];
  __shared__ int rsum[64][4];
  int b = blockIdx.y;
  int t = threadIdx.x;
  for (int i = t; i < N; i += 256) {
    float v_ = 0.f;
    #pragma unroll
    for (int nch = 0; nch < 8; ++nch)
      v_ += selpart[(size_t)nch * (B * N) + b * N + i];
    s[i] = v_;
  }
  __syncthreads();
  int i = blockIdx.x * 64 + (t & 63);
  int jc = t >> 6;
  float val = s[i];
  int r = 0;
  for (int j = jc * 512; j < jc * 512 + 512; ++j) {
    float sj = s[j];
    r += (sj > val || (sj == val && j < i)) ? 1 : 0;
  }
  rsum[t & 63][jc] = r;
  __syncthreads();
  if (t < 64) {
    int rank = rsum[t][0] + rsum[t][1] + rsum[t][2] + rsum[t][3];
    if (rank < M) idx[b * M + rank] = blockIdx.x * 64 + t;
  }
}

// ---- out partials via bf16 MFMA: m-tile 64 -> 512 blocks, 2/CU --------
// rinv computed inline with the exact rowred bits (same sum order + 1/s).
__global__ __launch_bounds__(256) void out_kernel(
    const float* __restrict__ Ae, const float* __restrict__ rowpart,
    const ushort_t* __restrict__ vbf, const int* __restrict__ idx,
    float* __restrict__ part) {
  __shared__ ushort_t sc[64][72];    // scores bf16, stride 144B (16B-aligned)
  __shared__ ushort_t vt[128][72];   // v bf16
  __shared__ int ridx[64];
  __shared__ float rinv[64];
  int t = threadIdx.x;
  int m0 = blockIdx.x * 64;
  int ns = blockIdx.y;
  int b = blockIdx.z;
  if (t < 64) {
    int r = idx[b * M + m0 + t];
    ridx[t] = r;
    float s = 0.f;
    #pragma unroll
    for (int sl = 0; sl < MBLK; ++sl)
      s += rowpart[(size_t)sl * (B * N) + b * N + r];
    rinv[t] = 1.0f / s;
  }
  __syncthreads();
  int lane = t & 63, w = t >> 6;
  int wc = w & 1, wm = w >> 1;       // c-half (64ch), m-half (32)
  int lr = lane & 31, lq = lane >> 5;
  f32x16 acc[2] = {};                // ct over two 32-ch subtiles
  int nbeg = ns * (N / NSPLIT);      // 256-wide K range
  for (int kb = 0; kb < N / NSPLIT; kb += 64) {
    __syncthreads();
    #pragma unroll
    for (int it = 0; it < 16; ++it) {   // scores: 64 rows x 64 cols
      int ii = it * 256 + t;            // 0..4095
      int r = ii >> 6, cn = ii & 63;
      float sv = Ae[((size_t)b * N + ridx[r]) * N + nbeg + kb + cn] * rinv[r];
      sc[r][cn] = f2bf(sv);
    }
    #pragma unroll
    for (int it = 0; it < 4; ++it) {    // v: 128 rows x 64 cols, short8 copies
      int u = it * 256 + t;             // 0..1023 vec-units
      int r = u >> 3, seg = u & 7;
      *(short8*)&vt[r][seg * 8] =
          *(const short8*)&vbf[((size_t)b * C + r) * N + nbeg + kb + seg * 8];
    }
    __syncthreads();
    #pragma unroll
    for (int ks = 0; ks < 4; ++ks) {
      short8 bf_ = *(const short8*)&sc[wm * 32 + lr][ks * 16 + lq * 8];
      #pragma unroll
      for (int ct = 0; ct < 2; ++ct) {
        short8 af = *(const short8*)&vt[wc * 64 + ct * 32 + lr][ks * 16 + lq * 8];
        acc[ct] = __builtin_amdgcn_mfma_f32_32x32x16_bf16(af, bf_, acc[ct], 0, 0, 0);
      }
    }
  }
  float* pb = part + ((size_t)ns * B + b) * C * M;
  #pragma unroll
  for (int ct = 0; ct < 2; ++ct) {
    #pragma unroll
    for (int reg = 0; reg < 16; ++reg) {
      int crow = wc * 64 + ct * 32 + (reg & 3) + 8 * (reg >> 2) + 4 * lq;
      pb[(size_t)crow * M + m0 + wm * 32 + lr] = acc[ct][reg];
    }
  }
}

// ---- deterministic reduce of the n-splits (float4, same per-elem order) --
__global__ __launch_bounds__(256) void reduce_kernel(
    const float* __restrict__ part, float* __restrict__ out) {
  int i = (blockIdx.x * 256 + threadIdx.x) * 4;
  float4 a = make_float4(0.f, 0.f, 0.f, 0.f);
  #pragma unroll
  for (int ns = 0; ns < NSPLIT; ++ns) {
    float4 p = *(const float4*)&part[(size_t)ns * (B * C * M) + i];
    a.x += p.x; a.y += p.y; a.z += p.z; a.w += p.w;
  }
  *(float4*)&out[i] = a;
}

extern "C" void kernel_launch(void* const* d_in, const int* in_sizes, int n_in,
                              void* d_out, int out_size, void* d_ws, size_t ws_size,
                              hipStream_t stream) {
  const float* x  = (const float*)d_in[0];
  const float* Wq = (const float*)d_in[1];
  const float* Wk = (const float*)d_in[2];
  const float* Wv = (const float*)d_in[3];
  float* out = (float*)d_out;

  const size_t TSZ = (size_t)B * N * C;
  ushort_t* split = (ushort_t*)d_ws;                 // 6 * TSZ bf16 = 25.2 MB
  ushort_t* vbf   = split + 6 * TSZ;                 // TSZ bf16 = 4.2 MB
  float* Ae       = (float*)(vbf + TSZ);             // 134.2 MB
  float* rowpart  = Ae + (size_t)B * N * N;          // 16 * B*N
  float* selpart  = rowpart + (size_t)MBLK * B * N;  // 8 * B*N
  int*   idx      = (int*)(selpart + (size_t)8 * B * N);  // B*M
  // part overlays split only (dead after energy); vbf stays live for out_kernel
  float* part     = (float*)split;

  qkv_kernel<<<dim3(16, N / 256, B), 256, 0, stream>>>(x, Wq, Wk, Wv, split, vbf);
  energy_kernel<<<dim3(N / 128, N / 128, B), 256, 0, stream>>>(split, Ae, rowpart);
  colsum_kernel<<<dim3(N / 256, 8, B), 256, 0, stream>>>(Ae, rowpart, selpart);
  topk_kernel<<<dim3(N / 64, B), 256, 0, stream>>>(selpart, idx);
  out_kernel<<<dim3(M / 64, NSPLIT, B), 256, 0, stream>>>(Ae, rowpart, vbf, idx, part);
  reduce_kernel<<<dim3(B * C * M / 1024), 256, 0, stream>>>(part, out);
}